// Round 3
// baseline (156.703 us; speedup 1.0000x reference)
//
#include <hip/hip_runtime.h>

typedef _Float16 f16;
typedef _Float16 f16x8 __attribute__((ext_vector_type(8)));
typedef _Float16 f16x4 __attribute__((ext_vector_type(4)));
typedef float f32x4 __attribute__((ext_vector_type(4)));

#define S_TOK 4096
#define NB 2
#define NH 8
#define DKH 64
#define DMODEL 512

static __device__ __forceinline__ f32x4 mfma16(f16x8 a, f16x8 b, f32x4 c) {
    return __builtin_amdgcn_mfma_f32_16x16x32_f16(a, b, c, 0, 0, 0);
}

// ---------------- fused QKV projection: out = x @ W^T (x:[8192][512] f32, W:[512][512] f32)
// mode 0 = Q (scaled 1/8 * log2(e), [bh][s][dk]); 1 = K; 2 = V ([bh][dk][s] transposed)
__global__ __launch_bounds__(256)
void proj_fused_kernel(const float* __restrict__ qx, const float* __restrict__ kx,
                       const float* __restrict__ vx,
                       const float* __restrict__ Wqp, const float* __restrict__ Wkp,
                       const float* __restrict__ Wvp,
                       f16* __restrict__ qo, f16* __restrict__ ko, f16* __restrict__ vo)
{
    const int mode = blockIdx.z;
    const float* x = (mode == 0) ? qx : (mode == 1) ? kx : vx;
    const float* W = (mode == 0) ? Wqp : (mode == 1) ? Wkp : Wvp;
    f16* out = (mode == 0) ? qo : (mode == 1) ? ko : vo;

    __shared__ f16 As[128 * 40];
    __shared__ f16 Bs[128 * 40];
    const int m0 = blockIdx.x * 128;
    const int n0 = blockIdx.y * 128;
    const int tid = threadIdx.x;
    const int wv = tid >> 6;
    const int lane = tid & 63;
    const int lr = lane & 15, lg = lane >> 4;
    const int wm = (wv >> 1) * 64, wn = (wv & 1) * 64;

    f32x4 acc[4][4];
#pragma unroll
    for (int i = 0; i < 4; ++i)
#pragma unroll
        for (int j = 0; j < 4; ++j) acc[i][j] = f32x4{0.f, 0.f, 0.f, 0.f};

    for (int kb = 0; kb < DMODEL; kb += 32) {
#pragma unroll
        for (int c = 0; c < 2; ++c) {
            const int chunk = tid + c * 256;
            const int row = chunk >> 2;
            const int col = (chunk & 3) * 8;
            const float* ga = x + (size_t)(m0 + row) * DMODEL + kb + col;
            float4 a0 = *(const float4*)ga;
            float4 a1 = *(const float4*)(ga + 4);
            f16x8 ha = { (f16)a0.x, (f16)a0.y, (f16)a0.z, (f16)a0.w,
                         (f16)a1.x, (f16)a1.y, (f16)a1.z, (f16)a1.w };
            *(f16x8*)(As + row * 40 + col) = ha;
            const float* gb = W + (size_t)(n0 + row) * DMODEL + kb + col;
            float4 b0 = *(const float4*)gb;
            float4 b1 = *(const float4*)(gb + 4);
            f16x8 hb = { (f16)b0.x, (f16)b0.y, (f16)b0.z, (f16)b0.w,
                         (f16)b1.x, (f16)b1.y, (f16)b1.z, (f16)b1.w };
            *(f16x8*)(Bs + row * 40 + col) = hb;
        }
        __syncthreads();
        f16x8 af[4], bf[4];
#pragma unroll
        for (int i = 0; i < 4; ++i)
            af[i] = *(const f16x8*)(As + (wm + 16 * i + lr) * 40 + 8 * lg);
#pragma unroll
        for (int j = 0; j < 4; ++j)
            bf[j] = *(const f16x8*)(Bs + (wn + 16 * j + lr) * 40 + 8 * lg);
#pragma unroll
        for (int i = 0; i < 4; ++i)
#pragma unroll
            for (int j = 0; j < 4; ++j)
                acc[i][j] = mfma16(af[i], bf[j], acc[i][j]);
        __syncthreads();
    }

#pragma unroll
    for (int i = 0; i < 4; ++i) {
        const int mbase = m0 + wm + 16 * i + 4 * lg;
#pragma unroll
        for (int j = 0; j < 4; ++j) {
            const int n = n0 + wn + 16 * j + lr;
            const int h = n >> 6, dk = n & 63;
            if (mode == 2) {
                const int b = mbase >> 12;
                const int s = mbase & 4095;
                f16x4 v4;
#pragma unroll
                for (int r = 0; r < 4; ++r) v4[r] = (f16)acc[i][j][r];
                *(f16x4*)(out + ((size_t)(b * NH + h) * DKH + dk) * S_TOK + s) = v4;
            } else {
                // Q: fold 1/sqrt(64) * log2(e) so attention uses exp2
                const float sc = (mode == 0) ? 0.1803368801111244f : 1.0f;
#pragma unroll
                for (int r = 0; r < 4; ++r) {
                    const int m = mbase + r;
                    const int b = m >> 12, s = m & 4095;
                    out[((size_t)(b * NH + h) * S_TOK + s) * DKH + dk] = (f16)(acc[i][j][r] * sc);
                }
            }
        }
    }
}

// ---------------- causal flash attention
// 512 blocks, 4 waves x 32 q-cols, KV=64 dbuf, defer-max, exp2, setprio.
// Block remap: XCD xc handles heads {2xc, 2xc+1} (K/V L2-resident); blocks bid and
// bid+256 land on the same CU (sequential-fill model) with qt and 31-qt -> balanced.
__global__ __launch_bounds__(256)
void attn_kernel(const f16* __restrict__ qh, const f16* __restrict__ kh,
                 const f16* __restrict__ vt, f16* __restrict__ ctx)
{
    __shared__ f16 Ks[2][64 * 64];    // [kv][dk], XOR-swizzled 16B granules
    __shared__ f16 Vs[2][64 * 64];    // [dk][kv], XOR-swizzled
    __shared__ f16 Ps[4][32 * 72];    // per-wave P [32 q][64 kv], stride 72

    const int bid = blockIdx.x;
    const int xc = bid & 7, w = bid >> 3;
    const int bh = 2 * xc + (w & 1);
    const int qi = (w >> 1) & 15;
    const int qt = (w >> 5) ? (31 - qi) : qi;
    const int q0 = qt * 128;
    const int nt = 2 * qt + 2;

    const int tid = threadIdx.x, wv = tid >> 6, lane = tid & 63;
    const int lr = lane & 15, lg = lane >> 4;

    const f16* Qp = qh + (size_t)bh * S_TOK * DKH;
    const f16* Kp = kh + (size_t)bh * S_TOK * DKH;
    const f16* Vp = vt + (size_t)bh * DKH * S_TOK;
    const int b = bh >> 3, h = bh & 7;

    // staging: 2 rounds of 32 rows; thread -> row srow0+32p, LDS granule sg, global granule sg^(row&7)
    const int srow0 = tid >> 3;              // 0..31
    const int sg = tid & 7;
    const int sgx = sg ^ (srow0 & 7);        // row&7 invariant across rounds
    const f16* Kg = Kp + srow0 * DKH + sgx * 8;
    const f16* Vg = Vp + (size_t)srow0 * S_TOK + sgx * 8;
    const int ld0 = srow0 * 64 + sg * 8;
    f16* Pw = &Ps[wv][0];

    // Q fragments: wave owns q cols [q0+32wv, +32), subtiles u=0,1
    const int qc0 = q0 + 32 * wv + lr;
    f16x8 aq[2][2];
#pragma unroll
    for (int u = 0; u < 2; ++u)
#pragma unroll
        for (int kk = 0; kk < 2; ++kk)
            aq[u][kk] = *(const f16x8*)(Qp + (size_t)(qc0 + 16 * u) * DKH + 32 * kk + 8 * lg);

    f32x4 acco[4][2];
#pragma unroll
    for (int c = 0; c < 4; ++c)
#pragma unroll
        for (int u = 0; u < 2; ++u) acco[c][u] = f32x4{0.f, 0.f, 0.f, 0.f};
    float mrow[2] = { -1e30f, -1e30f };
    float lrow[2] = { 0.f, 0.f };

    // stage tile 0 (fresh LDS, no barrier needed before writes)
    f16x8 k0a = *(const f16x8*)(Kg);
    f16x8 k0b = *(const f16x8*)(Kg + 32 * DKH);
    f16x8 v0a = *(const f16x8*)(Vg);
    f16x8 v0b = *(const f16x8*)(Vg + 32 * S_TOK);
    *(f16x8*)(&Ks[0][ld0]) = k0a;  *(f16x8*)(&Ks[0][ld0 + 2048]) = k0b;
    *(f16x8*)(&Vs[0][ld0]) = v0a;  *(f16x8*)(&Vs[0][ld0 + 2048]) = v0b;

    int cur = 0;
    for (int t = 0; t < nt; ++t) {
        const bool pre = (t + 1 < nt);
        f16x8 kna, knb, vna, vnb;
        if (pre) {  // issue next-tile loads early; land after barrier (T14)
            const int kvn = (t + 1) * 64;
            kna = *(const f16x8*)(Kg + (size_t)kvn * DKH);
            knb = *(const f16x8*)(Kg + (size_t)(kvn + 32) * DKH);
            vna = *(const f16x8*)(Vg + kvn);
            vnb = *(const f16x8*)(Vg + (size_t)32 * S_TOK + kvn);
        }
        __syncthreads();
        const f16* Kb = &Ks[cur][0];
        const f16* Vb = &Vs[cur][0];

        // S^T = K x Q^T : sc[c][u] = D[kv=16c+4lg+r][q=qc0+16u]
        f32x4 sc[4][2];
        __builtin_amdgcn_s_setprio(1);
#pragma unroll
        for (int c = 0; c < 4; ++c) {
            const int row = 16 * c + lr;
            const int rs = row & 7;
            f16x8 ak0 = *(const f16x8*)(Kb + row * 64 + ((lg ^ rs) * 8));
            f16x8 ak1 = *(const f16x8*)(Kb + row * 64 + (((lg + 4) ^ rs) * 8));
            sc[c][0] = mfma16(ak0, aq[0][0], f32x4{0.f, 0.f, 0.f, 0.f});
            sc[c][0] = mfma16(ak1, aq[0][1], sc[c][0]);
            sc[c][1] = mfma16(ak0, aq[1][0], f32x4{0.f, 0.f, 0.f, 0.f});
            sc[c][1] = mfma16(ak1, aq[1][1], sc[c][1]);
        }
        __builtin_amdgcn_s_setprio(0);

        if (t >= nt - 2) {  // diagonal tiles: causal mask
#pragma unroll
            for (int c = 0; c < 4; ++c)
#pragma unroll
                for (int u = 0; u < 2; ++u)
#pragma unroll
                    for (int r = 0; r < 4; ++r) {
                        const int kvg = t * 64 + 16 * c + 4 * lg + r;
                        sc[c][u][r] = (kvg > qc0 + 16 * u) ? -1e30f : sc[c][u][r];
                    }
        }

        // online softmax (log2 domain), kv-axis = 16 in-lane + lanes xor16/xor32
        float tm[2];
#pragma unroll
        for (int u = 0; u < 2; ++u) {
            float a0 = fmaxf(fmaxf(sc[0][u][0], sc[0][u][1]), fmaxf(sc[0][u][2], sc[0][u][3]));
            float a1 = fmaxf(fmaxf(sc[1][u][0], sc[1][u][1]), fmaxf(sc[1][u][2], sc[1][u][3]));
            float a2 = fmaxf(fmaxf(sc[2][u][0], sc[2][u][1]), fmaxf(sc[2][u][2], sc[2][u][3]));
            float a3 = fmaxf(fmaxf(sc[3][u][0], sc[3][u][1]), fmaxf(sc[3][u][2], sc[3][u][3]));
            float v = fmaxf(fmaxf(a0, a1), fmaxf(a2, a3));
            v = fmaxf(v, __shfl_xor(v, 16));
            v = fmaxf(v, __shfl_xor(v, 32));
            tm[u] = v;
        }
        const int okd = (tm[0] <= mrow[0] + 8.f) && (tm[1] <= mrow[1] + 8.f);
        if (!__all(okd)) {  // rescale (wave-uniform)
#pragma unroll
            for (int u = 0; u < 2; ++u) {
                const float mn = fmaxf(mrow[u], tm[u]);
                const float sf = exp2f(mrow[u] - mn);
                lrow[u] *= sf;
                mrow[u] = mn;
#pragma unroll
                for (int c = 0; c < 4; ++c) acco[c][u] *= sf;
            }
        }
#pragma unroll
        for (int u = 0; u < 2; ++u) {
            float ts = 0.f;
#pragma unroll
            for (int c = 0; c < 4; ++c) {
                f16x4 pk;
#pragma unroll
                for (int r = 0; r < 4; ++r) {
                    const float p = exp2f(sc[c][u][r] - mrow[u]);
                    ts += p;
                    pk[r] = (f16)p;
                }
                *(f16x4*)(Pw + (16 * u + lr) * 72 + 16 * c + 4 * lg) = pk;
            }
            ts += __shfl_xor(ts, 16);
            ts += __shfl_xor(ts, 32);
            lrow[u] += ts;
        }

        // PV: ctx^T += V^T x P^T
        f16x8 bp[2][2];
#pragma unroll
        for (int u = 0; u < 2; ++u)
#pragma unroll
            for (int kk = 0; kk < 2; ++kk)
                bp[u][kk] = *(const f16x8*)(Pw + (16 * u + lr) * 72 + 32 * kk + 8 * lg);
        __builtin_amdgcn_s_setprio(1);
#pragma unroll
        for (int c = 0; c < 4; ++c) {
            const int row = 16 * c + lr;
            const int rs = row & 7;
            f16x8 av0 = *(const f16x8*)(Vb + row * 64 + ((lg ^ rs) * 8));
            f16x8 av1 = *(const f16x8*)(Vb + row * 64 + (((lg + 4) ^ rs) * 8));
            acco[c][0] = mfma16(av0, bp[0][0], acco[c][0]);
            acco[c][0] = mfma16(av1, bp[0][1], acco[c][0]);
            acco[c][1] = mfma16(av0, bp[1][0], acco[c][1]);
            acco[c][1] = mfma16(av1, bp[1][1], acco[c][1]);
        }
        __builtin_amdgcn_s_setprio(0);

        if (pre) {  // write prefetched tile into the other buffer
            *(f16x8*)(&Ks[cur ^ 1][ld0]) = kna;  *(f16x8*)(&Ks[cur ^ 1][ld0 + 2048]) = knb;
            *(f16x8*)(&Vs[cur ^ 1][ld0]) = vna;  *(f16x8*)(&Vs[cur ^ 1][ld0 + 2048]) = vnb;
        }
        cur ^= 1;
    }

#pragma unroll
    for (int u = 0; u < 2; ++u) {
        const float invl = 1.0f / lrow[u];
        f16* cp = ctx + ((size_t)(b * S_TOK + qc0 + 16 * u)) * DMODEL + h * DKH;
#pragma unroll
        for (int c = 0; c < 4; ++c) {
            f16x4 o;
#pragma unroll
            for (int r = 0; r < 4; ++r) o[r] = (f16)(acco[c][u][r] * invl);
            *(f16x4*)(cp + 16 * c + 4 * lg) = o;
        }
    }
}

// ---------------- output projection: out = ctx(f16) @ W_o^T + b_o, fp32 out
__global__ __launch_bounds__(256)
void oproj_kernel(const f16* __restrict__ A, const float* __restrict__ W,
                  const float* __restrict__ bias, float* __restrict__ out)
{
    __shared__ f16 As[128 * 40];
    __shared__ f16 Bs[128 * 40];
    const int m0 = blockIdx.x * 128;
    const int n0 = blockIdx.y * 128;
    const int tid = threadIdx.x;
    const int wv = tid >> 6;
    const int lane = tid & 63;
    const int lr = lane & 15, lg = lane >> 4;
    const int wm = (wv >> 1) * 64, wn = (wv & 1) * 64;

    f32x4 acc[4][4];
#pragma unroll
    for (int i = 0; i < 4; ++i)
#pragma unroll
        for (int j = 0; j < 4; ++j) acc[i][j] = f32x4{0.f, 0.f, 0.f, 0.f};

    for (int kb = 0; kb < DMODEL; kb += 32) {
#pragma unroll
        for (int c = 0; c < 2; ++c) {
            const int chunk = tid + c * 256;
            const int row = chunk >> 2;
            const int col = (chunk & 3) * 8;
            *(f16x8*)(As + row * 40 + col) =
                *(const f16x8*)(A + (size_t)(m0 + row) * DMODEL + kb + col);
            const float* gb = W + (size_t)(n0 + row) * DMODEL + kb + col;
            float4 b0 = *(const float4*)gb;
            float4 b1 = *(const float4*)(gb + 4);
            f16x8 hb = { (f16)b0.x, (f16)b0.y, (f16)b0.z, (f16)b0.w,
                         (f16)b1.x, (f16)b1.y, (f16)b1.z, (f16)b1.w };
            *(f16x8*)(Bs + row * 40 + col) = hb;
        }
        __syncthreads();
        f16x8 af[4], bf[4];
#pragma unroll
        for (int i = 0; i < 4; ++i)
            af[i] = *(const f16x8*)(As + (wm + 16 * i + lr) * 40 + 8 * lg);
#pragma unroll
        for (int j = 0; j < 4; ++j)
            bf[j] = *(const f16x8*)(Bs + (wn + 16 * j + lr) * 40 + 8 * lg);
#pragma unroll
        for (int i = 0; i < 4; ++i)
#pragma unroll
            for (int j = 0; j < 4; ++j)
                acc[i][j] = mfma16(af[i], bf[j], acc[i][j]);
        __syncthreads();
    }

#pragma unroll
    for (int i = 0; i < 4; ++i) {
        const int mbase = m0 + wm + 16 * i + 4 * lg;
#pragma unroll
        for (int j = 0; j < 4; ++j) {
            const int n = n0 + wn + 16 * j + lr;
            const float bn = bias[n];
#pragma unroll
            for (int r = 0; r < 4; ++r) {
                const int m = mbase + r;
                out[(size_t)m * DMODEL + n] = acc[i][j][r] + bn;
            }
        }
    }
}

extern "C" void kernel_launch(void* const* d_in, const int* in_sizes, int n_in,
                              void* d_out, int out_size, void* d_ws, size_t ws_size,
                              hipStream_t stream) {
    const float* q  = (const float*)d_in[0];
    const float* k  = (const float*)d_in[1];
    const float* v  = (const float*)d_in[2];
    const float* Wq = (const float*)d_in[3];
    const float* Wk = (const float*)d_in[4];
    const float* Wv = (const float*)d_in[5];
    const float* Wo = (const float*)d_in[6];
    const float* bo = (const float*)d_in[7];
    float* out = (float*)d_out;

    const size_t per = (size_t)NB * NH * S_TOK * DKH;
    f16* qh  = (f16*)d_ws;
    f16* kh  = qh + per;
    f16* vt  = kh + per;
    f16* ctx = vt + per;

    proj_fused_kernel<<<dim3(64, 4, 3), 256, 0, stream>>>(q, k, v, Wq, Wk, Wv, qh, kh, vt);
    attn_kernel<<<dim3(512), 256, 0, stream>>>(qh, kh, vt, ctx);
    oproj_kernel<<<dim3(64, 4), 256, 0, stream>>>(ctx, Wo, bo, out);
}

// Round 5
// 132.730 us; speedup vs baseline: 1.1806x; 1.1806x over previous
//
#include <hip/hip_runtime.h>

typedef _Float16 f16;
typedef _Float16 f16x8 __attribute__((ext_vector_type(8)));
typedef _Float16 f16x4 __attribute__((ext_vector_type(4)));
typedef float f32x4 __attribute__((ext_vector_type(4)));
typedef float f32x16 __attribute__((ext_vector_type(16)));

#define S_TOK 4096
#define NB 2
#define NH 8
#define DKH 64
#define DMODEL 512

static __device__ __forceinline__ f32x4 mfma16(f16x8 a, f16x8 b, f32x4 c) {
    return __builtin_amdgcn_mfma_f32_16x16x32_f16(a, b, c, 0, 0, 0);
}
static __device__ __forceinline__ f32x16 mfma32(f16x8 a, f16x8 b, f32x16 c) {
    return __builtin_amdgcn_mfma_f32_32x32x16_f16(a, b, c, 0, 0, 0);
}

// ---------------- fused QKV projection: out = x @ W^T (x:[8192][512] f32, W:[512][512] f32)
// mode 0 = Q (scaled 1/8 * log2(e), [bh][s][dk]); 1 = K; 2 = V ([bh][dk][s] transposed)
__global__ __launch_bounds__(256)
void proj_fused_kernel(const float* __restrict__ qx, const float* __restrict__ kx,
                       const float* __restrict__ vx,
                       const float* __restrict__ Wqp, const float* __restrict__ Wkp,
                       const float* __restrict__ Wvp,
                       f16* __restrict__ qo, f16* __restrict__ ko, f16* __restrict__ vo)
{
    const int mode = blockIdx.z;
    const float* x = (mode == 0) ? qx : (mode == 1) ? kx : vx;
    const float* W = (mode == 0) ? Wqp : (mode == 1) ? Wkp : Wvp;
    f16* out = (mode == 0) ? qo : (mode == 1) ? ko : vo;

    __shared__ f16 As[128 * 40];
    __shared__ f16 Bs[128 * 40];
    const int m0 = blockIdx.x * 128;
    const int n0 = blockIdx.y * 128;
    const int tid = threadIdx.x;
    const int wv = tid >> 6;
    const int lane = tid & 63;
    const int lr = lane & 15, lg = lane >> 4;
    const int wm = (wv >> 1) * 64, wn = (wv & 1) * 64;

    f32x4 acc[4][4];
#pragma unroll
    for (int i = 0; i < 4; ++i)
#pragma unroll
        for (int j = 0; j < 4; ++j) acc[i][j] = f32x4{0.f, 0.f, 0.f, 0.f};

    for (int kb = 0; kb < DMODEL; kb += 32) {
#pragma unroll
        for (int c = 0; c < 2; ++c) {
            const int chunk = tid + c * 256;
            const int row = chunk >> 2;
            const int col = (chunk & 3) * 8;
            const float* ga = x + (size_t)(m0 + row) * DMODEL + kb + col;
            float4 a0 = *(const float4*)ga;
            float4 a1 = *(const float4*)(ga + 4);
            f16x8 ha = { (f16)a0.x, (f16)a0.y, (f16)a0.z, (f16)a0.w,
                         (f16)a1.x, (f16)a1.y, (f16)a1.z, (f16)a1.w };
            *(f16x8*)(As + row * 40 + col) = ha;
            const float* gb = W + (size_t)(n0 + row) * DMODEL + kb + col;
            float4 b0 = *(const float4*)gb;
            float4 b1 = *(const float4*)(gb + 4);
            f16x8 hb = { (f16)b0.x, (f16)b0.y, (f16)b0.z, (f16)b0.w,
                         (f16)b1.x, (f16)b1.y, (f16)b1.z, (f16)b1.w };
            *(f16x8*)(Bs + row * 40 + col) = hb;
        }
        __syncthreads();
        f16x8 af[4], bf[4];
#pragma unroll
        for (int i = 0; i < 4; ++i)
            af[i] = *(const f16x8*)(As + (wm + 16 * i + lr) * 40 + 8 * lg);
#pragma unroll
        for (int j = 0; j < 4; ++j)
            bf[j] = *(const f16x8*)(Bs + (wn + 16 * j + lr) * 40 + 8 * lg);
#pragma unroll
        for (int i = 0; i < 4; ++i)
#pragma unroll
            for (int j = 0; j < 4; ++j)
                acc[i][j] = mfma16(af[i], bf[j], acc[i][j]);
        __syncthreads();
    }

#pragma unroll
    for (int i = 0; i < 4; ++i) {
        const int mbase = m0 + wm + 16 * i + 4 * lg;
#pragma unroll
        for (int j = 0; j < 4; ++j) {
            const int n = n0 + wn + 16 * j + lr;
            const int h = n >> 6, dk = n & 63;
            if (mode == 2) {
                const int b = mbase >> 12;
                const int s = mbase & 4095;
                f16x4 v4;
#pragma unroll
                for (int r = 0; r < 4; ++r) v4[r] = (f16)acc[i][j][r];
                *(f16x4*)(out + ((size_t)(b * NH + h) * DKH + dk) * S_TOK + s) = v4;
            } else {
                // Q: fold 1/sqrt(64) * log2(e) so attention uses exp2
                const float sc = (mode == 0) ? 0.1803368801111244f : 1.0f;
#pragma unroll
                for (int r = 0; r < 4; ++r) {
                    const int m = mbase + r;
                    const int b = m >> 12, s = m & 4095;
                    out[((size_t)(b * NH + h) * S_TOK + s) * DKH + dk] = (f16)(acc[i][j][r] * sc);
                }
            }
        }
    }
}

// ---------------- causal flash attention, 32x32 MFMA, kv-chunked with 2-way merge
// 512 blocks x 256 thr (4 waves x 32 q-cols). Block (bh, j): segA=(qt=j, kv chunk0),
// segB=(qt=31-j, chunk1): (j+1)+(32-j) = 33 steps for EVERY block (scheduler-independent).
// Partials: O_norm (f16) + L = m + log2(l) (f32) per q-row, merged by merge_kernel.
__global__ __launch_bounds__(256, 3)
void attn_kernel(const f16* __restrict__ qh, const f16* __restrict__ kh,
                 const f16* __restrict__ vt, f16* __restrict__ pO, float* __restrict__ pL)
{
    __shared__ f16 Ks[2][64 * 64];   // [kv][dk], granule-XOR swizzled
    __shared__ f16 Vs[2][64 * 64];   // [dk][kv], granule-XOR swizzled
    __shared__ f16 Ps[4][32 * 72];   // per-wave P^T [q][kv], stride 72 (144B, 16B-aligned)

    const int bid = blockIdx.x;
    const int bh = 2 * (bid & 7) + ((bid >> 3) & 1);   // XCD affinity: 2 heads per XCD
    const int j = bid >> 4;                            // 0..31
    const int tid = threadIdx.x, wv = tid >> 6, lane = tid & 63;
    const int l31 = lane & 31, h = lane >> 5;

    const f16* Qp = qh + (size_t)bh * S_TOK * DKH;
    const f16* Kp = kh + (size_t)bh * S_TOK * DKH;
    const f16* Vp = vt + (size_t)bh * DKH * S_TOK;

    // staging map: thread -> (row, 2 LDS granule slots); slot sg holds global granule sg^(row&7)
    const int srow = tid >> 2;                       // 0..63
    const int s0 = (tid & 3) + 4 * ((tid >> 2) & 1); // slots spread over 0..7 per wave-instr
    const int s1 = s0 ^ 4;
    const int g0 = s0 ^ (srow & 7), g1 = s1 ^ (srow & 7);
    const int ldA = srow * 64 + s0 * 8, ldB = srow * 64 + s1 * 8;
    f16* Pw = &Ps[wv][0];

    for (int seg = 0; seg < 2; ++seg) {
        const int qt = seg ? (31 - j) : j;
        const int t0 = seg ? (qt + 1) : 0;
        const int t1 = seg ? (2 * qt + 2) : (j + 1);
        const int q0 = qt * 128;
        const int qw = q0 + 32 * wv + l31;
        const int unit = (bh * 32 + qt) * 2 + seg;

        // Q fragments (B-operand): col=q (lane&31), k = dk = 16s + 8h + jj
        f16x8 aq[4];
#pragma unroll
        for (int s = 0; s < 4; ++s)
            aq[s] = *(const f16x8*)(Qp + (size_t)qw * DKH + 16 * s + 8 * h);

        f32x16 accO0 = {}, accO1 = {};
        float mrow = -1e20f, lrow = 0.f;

        // stage tile t0 into buf 0
        f16x8 ka = *(const f16x8*)(Kp + (size_t)(64 * t0 + srow) * DKH + g0 * 8);
        f16x8 kb = *(const f16x8*)(Kp + (size_t)(64 * t0 + srow) * DKH + g1 * 8);
        f16x8 va = *(const f16x8*)(Vp + (size_t)srow * S_TOK + 64 * t0 + g0 * 8);
        f16x8 vb = *(const f16x8*)(Vp + (size_t)srow * S_TOK + 64 * t0 + g1 * 8);
        __syncthreads();   // previous segment fully done with LDS
        *(f16x8*)(&Ks[0][ldA]) = ka;  *(f16x8*)(&Ks[0][ldB]) = kb;
        *(f16x8*)(&Vs[0][ldA]) = va;  *(f16x8*)(&Vs[0][ldB]) = vb;

        int cur = 0;
        for (int t = t0; t < t1; ++t) {
            const bool pre = (t + 1 < t1);
            f16x8 kna, knb, vna, vnb;
            if (pre) {   // issue next-tile loads early (T14); land under compute
                kna = *(const f16x8*)(Kp + (size_t)(64 * (t + 1) + srow) * DKH + g0 * 8);
                knb = *(const f16x8*)(Kp + (size_t)(64 * (t + 1) + srow) * DKH + g1 * 8);
                vna = *(const f16x8*)(Vp + (size_t)srow * S_TOK + 64 * (t + 1) + g0 * 8);
                vnb = *(const f16x8*)(Vp + (size_t)srow * S_TOK + 64 * (t + 1) + g1 * 8);
            }
            __syncthreads();   // tile t staged; buf cur^1 free for writing
            const f16* Kb = &Ks[cur][0];
            const f16* Vb = &Vs[cur][0];

            // S^T = K x Q^T; accS[tt] D: row = kv = 32tt+(e&3)+8(e>>2)+4h, col = q = qw
            f32x16 accS0 = {}, accS1 = {};
            __builtin_amdgcn_s_setprio(1);
#pragma unroll
            for (int s = 0; s < 4; ++s) {
                f16x8 ak0 = *(const f16x8*)(Kb + (l31) * 64 + ((2 * s + h) ^ (l31 & 7)) * 8);
                f16x8 ak1 = *(const f16x8*)(Kb + (32 + l31) * 64 + ((2 * s + h) ^ (l31 & 7)) * 8);
                accS0 = mfma32(ak0, aq[s], accS0);
                accS1 = mfma32(ak1, aq[s], accS1);
            }
            __builtin_amdgcn_s_setprio(0);

            if (t >= 2 * qt) {   // diagonal: causal mask
#pragma unroll
                for (int e = 0; e < 16; ++e) {
                    const int kvb = 64 * t + (e & 3) + 8 * (e >> 2) + 4 * h;
                    accS0[e] = (kvb > qw) ? -1e30f : accS0[e];
                    accS1[e] = (kvb + 32 > qw) ? -1e30f : accS1[e];
                }
            }

            // online softmax: kv axis = 32 in-lane + partner half (xor 32)
            float tm = -1e30f;
#pragma unroll
            for (int e = 0; e < 16; ++e) tm = fmaxf(tm, fmaxf(accS0[e], accS1[e]));
            tm = fmaxf(tm, __shfl_xor(tm, 32));
            if (!__all(tm <= mrow + 8.f)) {   // defer-max (T13)
                const float mn = fmaxf(mrow, tm);
                const float sf = exp2f(mrow - mn);
                lrow *= sf;
                accO0 *= sf;  accO1 *= sf;
                mrow = mn;
            }
            // p = exp2(s - m) -> f16 -> per-wave LDS P^T [q=l31][kv]
            float ts = 0.f;
#pragma unroll
            for (int g = 0; g < 4; ++g) {
                f16x4 u, u2;
#pragma unroll
                for (int r = 0; r < 4; ++r) {
                    const float p = exp2f(accS0[4 * g + r] - mrow);
                    ts += p;
                    u[r] = (f16)p;
                    const float pq = exp2f(accS1[4 * g + r] - mrow);
                    ts += pq;
                    u2[r] = (f16)pq;
                }
                *(f16x4*)(Pw + l31 * 72 + 8 * g + 4 * h) = u;
                *(f16x4*)(Pw + l31 * 72 + 32 + 8 * g + 4 * h) = u2;
            }
            ts += __shfl_xor(ts, 32);
            lrow += ts;

            // PV: ctx^T += V^T x P^T (P B-frag: col=q=l31, k=kv=16s+8h+jj)
            __builtin_amdgcn_s_setprio(1);
#pragma unroll
            for (int s = 0; s < 4; ++s) {
                f16x8 bp = *(const f16x8*)(Pw + l31 * 72 + 16 * s + 8 * h);
                f16x8 av0 = *(const f16x8*)(Vb + (l31) * 64 + ((2 * s + h) ^ (l31 & 7)) * 8);
                f16x8 av1 = *(const f16x8*)(Vb + (32 + l31) * 64 + ((2 * s + h) ^ (l31 & 7)) * 8);
                accO0 = mfma32(av0, bp, accO0);
                accO1 = mfma32(av1, bp, accO1);
            }
            __builtin_amdgcn_s_setprio(0);

            if (pre) {   // write prefetched tile into other buffer
                *(f16x8*)(&Ks[cur ^ 1][ldA]) = kna;  *(f16x8*)(&Ks[cur ^ 1][ldB]) = knb;
                *(f16x8*)(&Vs[cur ^ 1][ldA]) = vna;  *(f16x8*)(&Vs[cur ^ 1][ldB]) = vnb;
            }
            cur ^= 1;
        }

        // write partial: O_norm f16 + L = m + log2(l)
        const float invl = (lrow > 0.f) ? (1.f / lrow) : 0.f;
        f16* Ob = pO + ((size_t)unit * 128 + (32 * wv + l31)) * DKH;
#pragma unroll
        for (int g = 0; g < 4; ++g) {
            f16x4 o0, o1;
#pragma unroll
            for (int r = 0; r < 4; ++r) {
                o0[r] = (f16)(accO0[4 * g + r] * invl);
                o1[r] = (f16)(accO1[4 * g + r] * invl);
            }
            *(f16x4*)(Ob + 8 * g + 4 * h) = o0;
            *(f16x4*)(Ob + 32 + 8 * g + 4 * h) = o1;
        }
        if (h == 0)
            pL[unit * 128 + 32 * wv + l31] =
                (lrow > 0.f) ? (mrow + __log2f(lrow)) : -1e30f;
    }
}

// ---------------- merge 2 kv-chunk partials per q-row -> ctx f16
__global__ __launch_bounds__(256)
void merge_kernel(const f16* __restrict__ pO, const float* __restrict__ pL,
                  f16* __restrict__ ctx)
{
    const int tid = threadIdx.x;
    const int R = blockIdx.x * 32 + (tid >> 3);   // row id 0..65535
    const int dkg = tid & 7;
    const int bh = R >> 12, q = R & 4095;
    const int qt = q >> 7, qi = q & 127;
    const int u0 = (bh * 32 + qt) * 2, u1 = u0 + 1;

    const float L0 = pL[u0 * 128 + qi];
    const float L1 = pL[u1 * 128 + qi];
    const float Lm = fmaxf(L0, L1);
    const float w0 = exp2f(L0 - Lm);
    const float w1 = exp2f(L1 - Lm);
    const float inv = 1.f / (w0 + w1);

    f16x8 a = *(const f16x8*)(pO + ((size_t)u0 * 128 + qi) * DKH + dkg * 8);
    f16x8 b = *(const f16x8*)(pO + ((size_t)u1 * 128 + qi) * DKH + dkg * 8);
    f16x8 o;
#pragma unroll
    for (int i = 0; i < 8; ++i)
        o[i] = (f16)((w0 * (float)a[i] + w1 * (float)b[i]) * inv);

    const int bb = bh >> 3, hh = bh & 7;
    *(f16x8*)(ctx + ((size_t)(bb * S_TOK + q)) * DMODEL + hh * DKH + dkg * 8) = o;
}

// ---------------- output projection: out = ctx(f16) @ W_o^T + b_o, fp32 out
__global__ __launch_bounds__(256)
void oproj_kernel(const f16* __restrict__ A, const float* __restrict__ W,
                  const float* __restrict__ bias, float* __restrict__ out)
{
    __shared__ f16 As[128 * 40];
    __shared__ f16 Bs[128 * 40];
    const int m0 = blockIdx.x * 128;
    const int n0 = blockIdx.y * 128;
    const int tid = threadIdx.x;
    const int wv = tid >> 6;
    const int lane = tid & 63;
    const int lr = lane & 15, lg = lane >> 4;
    const int wm = (wv >> 1) * 64, wn = (wv & 1) * 64;

    f32x4 acc[4][4];
#pragma unroll
    for (int i = 0; i < 4; ++i)
#pragma unroll
        for (int j = 0; j < 4; ++j) acc[i][j] = f32x4{0.f, 0.f, 0.f, 0.f};

    for (int kb = 0; kb < DMODEL; kb += 32) {
#pragma unroll
        for (int c = 0; c < 2; ++c) {
            const int chunk = tid + c * 256;
            const int row = chunk >> 2;
            const int col = (chunk & 3) * 8;
            *(f16x8*)(As + row * 40 + col) =
                *(const f16x8*)(A + (size_t)(m0 + row) * DMODEL + kb + col);
            const float* gb = W + (size_t)(n0 + row) * DMODEL + kb + col;
            float4 b0 = *(const float4*)gb;
            float4 b1 = *(const float4*)(gb + 4);
            f16x8 hb = { (f16)b0.x, (f16)b0.y, (f16)b0.z, (f16)b0.w,
                         (f16)b1.x, (f16)b1.y, (f16)b1.z, (f16)b1.w };
            *(f16x8*)(Bs + row * 40 + col) = hb;
        }
        __syncthreads();
        f16x8 af[4], bf[4];
#pragma unroll
        for (int i = 0; i < 4; ++i)
            af[i] = *(const f16x8*)(As + (wm + 16 * i + lr) * 40 + 8 * lg);
#pragma unroll
        for (int j = 0; j < 4; ++j)
            bf[j] = *(const f16x8*)(Bs + (wn + 16 * j + lr) * 40 + 8 * lg);
#pragma unroll
        for (int i = 0; i < 4; ++i)
#pragma unroll
            for (int j = 0; j < 4; ++j)
                acc[i][j] = mfma16(af[i], bf[j], acc[i][j]);
        __syncthreads();
    }

#pragma unroll
    for (int i = 0; i < 4; ++i) {
        const int mbase = m0 + wm + 16 * i + 4 * lg;
#pragma unroll
        for (int j = 0; j < 4; ++j) {
            const int n = n0 + wn + 16 * j + lr;
            const float bn = bias[n];
#pragma unroll
            for (int r = 0; r < 4; ++r) {
                const int m = mbase + r;
                out[(size_t)m * DMODEL + n] = acc[i][j][r] + bn;
            }
        }
    }
}

extern "C" void kernel_launch(void* const* d_in, const int* in_sizes, int n_in,
                              void* d_out, int out_size, void* d_ws, size_t ws_size,
                              hipStream_t stream) {
    const float* q  = (const float*)d_in[0];
    const float* k  = (const float*)d_in[1];
    const float* v  = (const float*)d_in[2];
    const float* Wq = (const float*)d_in[3];
    const float* Wk = (const float*)d_in[4];
    const float* Wv = (const float*)d_in[5];
    const float* Wo = (const float*)d_in[6];
    const float* bo = (const float*)d_in[7];
    float* out = (float*)d_out;

    const size_t per = (size_t)NB * NH * S_TOK * DKH;   // 4,194,304 f16
    f16* qh  = (f16*)d_ws;
    f16* kh  = qh + per;
    f16* vt  = kh + per;
    f16* ctx = vt + per;
    f16* pO  = ctx + per;                // 1024 units x 128 q x 64 dk f16 = 16 MB
    float* pL = (float*)(pO + (size_t)1024 * 128 * 64);  // 512 KB

    proj_fused_kernel<<<dim3(64, 4, 3), 256, 0, stream>>>(q, k, v, Wq, Wk, Wv, qh, kh, vt);
    attn_kernel<<<dim3(512), 256, 0, stream>>>(qh, kh, vt, pO, pL);
    merge_kernel<<<dim3(2048), 256, 0, stream>>>(pO, pL, ctx);
    oproj_kernel<<<dim3(64, 4), 256, 0, stream>>>(ctx, Wo, bo, out);
}